// Round 2
// 210.090 us; speedup vs baseline: 1.2129x; 1.2129x over previous
//
#include <hip/hip_runtime.h>
#include <math.h>

#define KK 48
#define TT 1024
#define BB 512
#define START_TAG 46
#define END_TAG 47
#define NSEG 4
#define OWN (TT / NSEG)     // 256 owned steps per segment wave
#define WARM 16             // warm-up steps for segments 1..3 (direction mixing)

typedef _Float16 h2 __attribute__((ext_vector_type(2)));

#if defined(__has_builtin)
#if __has_builtin(__builtin_amdgcn_fdot2)
#define HAVE_FDOT2 1
#endif
#endif

// v_dot2_f32_f16: c + a.x*b.x + a.y*b.y (f32 accumulate)
__device__ __forceinline__ float fdot2(h2 a, h2 b, float c) {
#ifdef HAVE_FDOT2
    return __builtin_amdgcn_fdot2(a, b, c, false);
#else
    return c + (float)a.x * (float)b.x + (float)a.y * (float)b.y;
#endif
}

// ---------------------------------------------------------------------------
// R11: segmented forward recurrence -> 2 waves/SIMD.
//
// R9's limit: 694 cyc/step with 1024 chains on 1024 SIMDs (1 wave/SIMD);
// latency-bound, VALUBusy 37%. R10's intra-wave ILP-2 cannot beat
// max(2*issue, L) = L (and its LDS broadcast broke; reverted). R11 keeps
// R9's PROVEN per-step datapath (24 dot2 on packed-f16 broadcast state, exact
// pow-2 ledger, DPP pack + 24 readlanes) and creates more chains instead:
// forward-only, each sentence split into NSEG=4 segments. Segments 1..3 start
// from all-ones and run WARM=16 mixing steps (E is near-rank-1: Hilbert
// contraction <=0.38/step -> direction error ~2e-7); the unknown per-segment
// scalar is recovered exactly at combine via lane-0 residual ratios:
//   alpha_1024 ~= u3 * 2^{sum Ow} * prod_{w=1..3} u_{w-1}[0]/q_w[0]
// where q_w = residual right after warm-up (t=256w), u_w = final residual,
// O_w = exact int ledger over owned steps only. logZ error ~1e-6 on top of
// R9's f16-E systematic ~absmax 32 (threshold 90.24).
// Grid: 512 blocks x 256 threads (4 segment waves); 2048 waves = 2/SIMD.
// Predicted: 272 steps x ~694 cyc = ~79 us dispatch (vs 148).
// ---------------------------------------------------------------------------

template <bool EXACT>
__device__ __forceinline__ void run_seg(const float* __restrict__ fb,
                                        const float* __restrict__ trans,
                                        int ci, bool evenLane,
                                        int r0, int ngrp,
                                        float& sOut, int& oOut, float& q0Out) {
    // E rows in f16 pairs: Eh[c] = (exp(trans[ci][2c]), exp(trans[ci][2c+1]))
    h2 Eh[24];
    #pragma unroll
    for (int c = 0; c < 24; ++c) {
        float e0 = __expf(trans[ci * KK + 2 * c]);
        float e1 = __expf(trans[ci * KK + 2 * c + 1]);
        Eh[c] = (h2){(_Float16)e0, (_Float16)e1};
    }

    // packed-f16 broadcast state: EXACT -> e_START; warm-up -> all-ones
    int au[24];
    #pragma unroll
    for (int c = 0; c < 24; ++c)
        au[c] = EXACT ? ((c == 23) ? 0x00003C00 : 0) : 0x3C003C00;

    float s = 0.0f;
    int esum = 0;
    int eswm = 0;        // ledger at warm-up boundary (0 for EXACT)
    float q0 = 1.0f;     // lane-0 residual at warm-up boundary (unused EXACT)

    // feats prefetch: groups of 4 rows
    float fr[4];
    #pragma unroll
    for (int k = 0; k < 4; ++k) fr[k] = fb[(r0 + k) * KK + ci];

    const int WG = WARM / 4;
    for (int g = 0; g < ngrp; ++g) {
        float fn[4] = {0.f, 0.f, 0.f, 0.f};
        if (g < ngrp - 1) {
            #pragma unroll
            for (int k = 0; k < 4; ++k)
                fn[k] = fb[(r0 + (g + 1) * 4 + k) * KK + ci];
        }
        float ef[4];
        #pragma unroll
        for (int k = 0; k < 4; ++k) ef[k] = __expf(fr[k]);

        #pragma unroll
        for (int k = 0; k < 4; ++k) {
            // s_i = sum_c dot2(Eh[c], au[c]) : 4 chains x 6
            float a0 = 0.f, a1 = 0.f, a2 = 0.f, a3 = 0.f;
            #pragma unroll
            for (int c = 0; c < 6; ++c) {
                a0 = fdot2(Eh[4 * c + 0], __builtin_bit_cast(h2, au[4 * c + 0]), a0);
                a1 = fdot2(Eh[4 * c + 1], __builtin_bit_cast(h2, au[4 * c + 1]), a1);
                a2 = fdot2(Eh[4 * c + 2], __builtin_bit_cast(h2, au[4 * c + 2]), a2);
                a3 = fdot2(Eh[4 * c + 3], __builtin_bit_cast(h2, au[4 * c + 3]), a3);
            }
            float sr = ((a0 + a1) + (a2 + a3)) * ef[k];
            // uniform pow-2 rescale EVERY step (f16 range), exact int ledger
            int rl0 = __builtin_amdgcn_readlane(__float_as_int(sr), 0);
            int e0 = ((rl0 >> 23) & 0xff) - 127;
            esum += e0;
            s = sr * __int_as_float((127 - e0) << 23);
            // pack pair {s_2c, s_2c+1} via DPP partner swap, broadcast 24 dwords
            int pb = __builtin_amdgcn_update_dpp(
                0, __float_as_int(s), 0xB1, 0xF, 0xF, true);  // quad_perm 1,0,3,2
            float pv = __int_as_float(pb);
            float lo = evenLane ? s : pv;
            float hi = evenLane ? pv : s;
            int pkb = __builtin_bit_cast(int, __builtin_amdgcn_cvt_pkrtz(lo, hi));
            #pragma unroll
            for (int c = 0; c < 24; ++c)
                au[c] = __builtin_amdgcn_readlane(pkb, 2 * c);
        }

        if (!EXACT && g == WG - 1) {   // wave-uniform, taken once
            eswm = esum;
            q0 = __int_as_float(__builtin_amdgcn_readfirstlane(__float_as_int(s)));
        }

        #pragma unroll
        for (int k = 0; k < 4; ++k) fr[k] = fn[k];
    }
    sOut = s;                // residual direction at segment end (lane0 in [1,2))
    oOut = esum - eswm;      // exact owned-steps ledger
    q0Out = q0;
}

__global__ __launch_bounds__(256)
__attribute__((amdgpu_waves_per_eu(2)))
void crf_kernel(const float* __restrict__ feats,
                const float* __restrict__ trans,
                const int* __restrict__ tags,
                float* __restrict__ out) {
    const int b = blockIdx.x;
    const int tid = threadIdx.x;
    const int wave = tid >> 6;          // segment index 0..3
    const int lane = tid & 63;
    const int ci = (lane < KK) ? lane : 0;
    const bool evenLane = (lane & 1) == 0;
    const float* fb = feats + (size_t)b * TT * KK;
    const int* tg = tags + b * TT;

    __shared__ float shU[NSEG][64];   // final residual vectors
    __shared__ int shO[NSEG];         // owned ledgers
    __shared__ float shQ0[NSEG];      // lane-0 residual at warm-up boundary
    __shared__ float shGp[NSEG];      // gold partials

    float sF; int oW; float q0;
    if (wave == 0) run_seg<true >(fb, trans, ci, evenLane, 0, OWN / 4, sF, oW, q0);
    else           run_seg<false>(fb, trans, ci, evenLane,
                                  wave * OWN - WARM, (OWN + WARM) / 4, sF, oW, q0);

    shU[wave][lane] = sF;
    if (lane == 0) { shO[wave] = oW; shQ0[wave] = q0; }

    // ---- gold gather: 1024 t's over 256 threads (after the hot loop) ----
    float gacc = 0.0f;
    #pragma unroll
    for (int r = 0; r < TT / 256; ++r) {
        int t = tid + r * 256;
        int cur = tg[t];
        int prev = (t == 0) ? START_TAG : tg[t - 1];
        gacc += trans[cur * KK + prev] + fb[(size_t)t * KK + cur];
    }
    #pragma unroll
    for (int off = 32; off; off >>= 1) gacc += __shfl_xor(gacc, off, 64);
    if (lane == 0) shGp[wave] = gacc;

    __syncthreads();

    if (tid < 64) {
        // Z-direction combine: sum_i exp(trans[END][i]) * u3[i]
        float val = (lane < KK) ? __expf(trans[END_TAG * KK + lane]) * shU[NSEG - 1][lane]
                                : 0.0f;
        #pragma unroll
        for (int off = 32; off; off >>= 1) val += __shfl_xor(val, off, 64);
        if (lane == 0) {
            float logz = __logf(val) +
                         (float)(shO[0] + shO[1] + shO[2] + shO[3]) * 0.6931471805599453f;
            // scalar stitches: alpha scale handoff across segment boundaries
            #pragma unroll
            for (int w = 1; w < NSEG; ++w)
                logz += __logf(shU[w - 1][0]) - __logf(shQ0[w]);
            float gold = shGp[0] + shGp[1] + shGp[2] + shGp[3] +
                         trans[END_TAG * KK + tg[TT - 1]];
            out[b] = logz - gold;
        }
    }
}

extern "C" void kernel_launch(void* const* d_in, const int* in_sizes, int n_in,
                              void* d_out, int out_size, void* d_ws, size_t ws_size,
                              hipStream_t stream) {
    const float* feats = (const float*)d_in[0];
    const float* trans = (const float*)d_in[1];
    const int* tags = (const int*)d_in[2];
    float* out = (float*)d_out;

    crf_kernel<<<BB, 256, 0, stream>>>(feats, trans, tags, out);
}

// Round 3
// 199.820 us; speedup vs baseline: 1.2752x; 1.0514x over previous
//
#include <hip/hip_runtime.h>
#include <math.h>

#define KK 48
#define TT 1024
#define BB 512
#define START_TAG 46
#define END_TAG 47
#define NSEG 8
#define OWN (TT / NSEG)     // 128 owned steps per segment wave
#define WARM 16             // warm-up steps for segments 1..7 (direction mixing)
#define NTHR (NSEG * 64)

typedef _Float16 h2 __attribute__((ext_vector_type(2)));

#if defined(__has_builtin)
#if __has_builtin(__builtin_amdgcn_fdot2)
#define HAVE_FDOT2 1
#endif
#endif

// v_dot2_f32_f16: c + a.x*b.x + a.y*b.y (f32 accumulate)
__device__ __forceinline__ float fdot2(h2 a, h2 b, float c) {
#ifdef HAVE_FDOT2
    return __builtin_amdgcn_fdot2(a, b, c, false);
#else
    return c + (float)a.x * (float)b.x + (float)a.y * (float)b.y;
#endif
}

// ---------------------------------------------------------------------------
// R12: NSEG=8 segmented forward recurrence -> 4 waves/SIMD.
//
// R11 (NSEG=4, 2 waves/SIMD) measured 104.6 us: per-wave-step 694 -> 461 cyc,
// VALUBusy 37 -> 55%. Fit: step ~= 430 cyc unfilled stall + n*254 issue; the
// stall partially fills with co-residency, so take the next notch. NSEG=8:
// 4096 waves = 4/SIMD (VGPR=32, no occupancy limit), 144 steps/wave.
// Per-step datapath byte-identical to R9/R11 (24 dot2 on packed-f16 broadcast
// state, exact pow-2 ledger, DPP pack + 24 readlanes). Segments 1..7 start
// all-ones, WARM=16 mixing steps (contraction ~0.38/step -> ~2e-7 direction
// err); per-boundary scalar recovered at combine via lane-0 residual ratios.
// Predicted: 65-85 us dispatch, VALUBusy 72-90%, Occupancy ~39%, absmax 32.
// ---------------------------------------------------------------------------

template <bool EXACT>
__device__ __forceinline__ void run_seg(const float* __restrict__ fb,
                                        const float* __restrict__ trans,
                                        int ci, bool evenLane,
                                        int r0, int ngrp,
                                        float& sOut, int& oOut, float& q0Out) {
    // E rows in f16 pairs: Eh[c] = (exp(trans[ci][2c]), exp(trans[ci][2c+1]))
    h2 Eh[24];
    #pragma unroll
    for (int c = 0; c < 24; ++c) {
        float e0 = __expf(trans[ci * KK + 2 * c]);
        float e1 = __expf(trans[ci * KK + 2 * c + 1]);
        Eh[c] = (h2){(_Float16)e0, (_Float16)e1};
    }

    // packed-f16 broadcast state: EXACT -> e_START; warm-up -> all-ones
    int au[24];
    #pragma unroll
    for (int c = 0; c < 24; ++c)
        au[c] = EXACT ? ((c == 23) ? 0x00003C00 : 0) : 0x3C003C00;

    float s = 0.0f;
    int esum = 0;
    int eswm = 0;        // ledger at warm-up boundary (0 for EXACT)
    float q0 = 1.0f;     // lane-0 residual at warm-up boundary (unused EXACT)

    // feats prefetch: groups of 4 rows
    float fr[4];
    #pragma unroll
    for (int k = 0; k < 4; ++k) fr[k] = fb[(r0 + k) * KK + ci];

    const int WG = WARM / 4;
    for (int g = 0; g < ngrp; ++g) {
        float fn[4] = {0.f, 0.f, 0.f, 0.f};
        if (g < ngrp - 1) {
            #pragma unroll
            for (int k = 0; k < 4; ++k)
                fn[k] = fb[(r0 + (g + 1) * 4 + k) * KK + ci];
        }
        float ef[4];
        #pragma unroll
        for (int k = 0; k < 4; ++k) ef[k] = __expf(fr[k]);

        #pragma unroll
        for (int k = 0; k < 4; ++k) {
            // s_i = sum_c dot2(Eh[c], au[c]) : 4 chains x 6
            float a0 = 0.f, a1 = 0.f, a2 = 0.f, a3 = 0.f;
            #pragma unroll
            for (int c = 0; c < 6; ++c) {
                a0 = fdot2(Eh[4 * c + 0], __builtin_bit_cast(h2, au[4 * c + 0]), a0);
                a1 = fdot2(Eh[4 * c + 1], __builtin_bit_cast(h2, au[4 * c + 1]), a1);
                a2 = fdot2(Eh[4 * c + 2], __builtin_bit_cast(h2, au[4 * c + 2]), a2);
                a3 = fdot2(Eh[4 * c + 3], __builtin_bit_cast(h2, au[4 * c + 3]), a3);
            }
            float sr = ((a0 + a1) + (a2 + a3)) * ef[k];
            // uniform pow-2 rescale EVERY step (f16 range), exact int ledger
            int rl0 = __builtin_amdgcn_readlane(__float_as_int(sr), 0);
            int e0 = ((rl0 >> 23) & 0xff) - 127;
            esum += e0;
            s = sr * __int_as_float((127 - e0) << 23);
            // pack pair {s_2c, s_2c+1} via DPP partner swap, broadcast 24 dwords
            int pb = __builtin_amdgcn_update_dpp(
                0, __float_as_int(s), 0xB1, 0xF, 0xF, true);  // quad_perm 1,0,3,2
            float pv = __int_as_float(pb);
            float lo = evenLane ? s : pv;
            float hi = evenLane ? pv : s;
            int pkb = __builtin_bit_cast(int, __builtin_amdgcn_cvt_pkrtz(lo, hi));
            #pragma unroll
            for (int c = 0; c < 24; ++c)
                au[c] = __builtin_amdgcn_readlane(pkb, 2 * c);
        }

        if (!EXACT && g == WG - 1) {   // wave-uniform, taken once
            eswm = esum;
            q0 = __int_as_float(__builtin_amdgcn_readfirstlane(__float_as_int(s)));
        }

        #pragma unroll
        for (int k = 0; k < 4; ++k) fr[k] = fn[k];
    }
    sOut = s;                // residual direction at segment end (lane0 in [1,2))
    oOut = esum - eswm;      // exact owned-steps ledger
    q0Out = q0;
}

__global__ __launch_bounds__(NTHR)
__attribute__((amdgpu_waves_per_eu(4)))
void crf_kernel(const float* __restrict__ feats,
                const float* __restrict__ trans,
                const int* __restrict__ tags,
                float* __restrict__ out) {
    const int b = blockIdx.x;
    const int tid = threadIdx.x;
    const int wave = tid >> 6;          // segment index 0..NSEG-1
    const int lane = tid & 63;
    const int ci = (lane < KK) ? lane : 0;
    const bool evenLane = (lane & 1) == 0;
    const float* fb = feats + (size_t)b * TT * KK;
    const int* tg = tags + b * TT;

    __shared__ float shU[NSEG][64];   // final residual vectors
    __shared__ int shO[NSEG];         // owned ledgers
    __shared__ float shQ0[NSEG];      // lane-0 residual at warm-up boundary
    __shared__ float shGp[NSEG];      // gold partials

    float sF; int oW; float q0;
    if (wave == 0) run_seg<true >(fb, trans, ci, evenLane, 0, OWN / 4, sF, oW, q0);
    else           run_seg<false>(fb, trans, ci, evenLane,
                                  wave * OWN - WARM, (OWN + WARM) / 4, sF, oW, q0);

    shU[wave][lane] = sF;
    if (lane == 0) { shO[wave] = oW; shQ0[wave] = q0; }

    // ---- gold gather: 1024 t's over NTHR threads (after the hot loop) ----
    float gacc = 0.0f;
    #pragma unroll
    for (int r = 0; r < TT / NTHR; ++r) {
        int t = tid + r * NTHR;
        int cur = tg[t];
        int prev = (t == 0) ? START_TAG : tg[t - 1];
        gacc += trans[cur * KK + prev] + fb[(size_t)t * KK + cur];
    }
    #pragma unroll
    for (int off = 32; off; off >>= 1) gacc += __shfl_xor(gacc, off, 64);
    if (lane == 0) shGp[wave] = gacc;

    __syncthreads();

    if (tid < 64) {
        // Z-direction combine: sum_i exp(trans[END][i]) * u_{NSEG-1}[i]
        float val = (lane < KK) ? __expf(trans[END_TAG * KK + lane]) * shU[NSEG - 1][lane]
                                : 0.0f;
        #pragma unroll
        for (int off = 32; off; off >>= 1) val += __shfl_xor(val, off, 64);
        if (lane == 0) {
            int osum = 0;
            float gold = trans[END_TAG * KK + tg[TT - 1]];
            #pragma unroll
            for (int w = 0; w < NSEG; ++w) { osum += shO[w]; gold += shGp[w]; }
            float logz = __logf(val) + (float)osum * 0.6931471805599453f;
            // scalar stitches: alpha scale handoff across segment boundaries
            #pragma unroll
            for (int w = 1; w < NSEG; ++w)
                logz += __logf(shU[w - 1][0]) - __logf(shQ0[w]);
            out[b] = logz - gold;
        }
    }
}

extern "C" void kernel_launch(void* const* d_in, const int* in_sizes, int n_in,
                              void* d_out, int out_size, void* d_ws, size_t ws_size,
                              hipStream_t stream) {
    const float* feats = (const float*)d_in[0];
    const float* trans = (const float*)d_in[1];
    const int* tags = (const int*)d_in[2];
    float* out = (float*)d_out;

    crf_kernel<<<BB, NTHR, 0, stream>>>(feats, trans, tags, out);
}